// Round 1
// baseline (224.350 us; speedup 1.0000x reference)
//
#include <hip/hip_runtime.h>
#include <math.h>

#define NROWS 4000000
#define DCOV  64
#define NSEG  100000

// ---------------------------------------------------------------------------
// Kernel 1: logits[i] = dot(X[i,:], w) + b
// Wave-cooperative: each 64-lane wave loads one float4 per lane = 1KB
// contiguous = 4 rows (16 lanes per row). Reduce within the 16-lane group.
// ---------------------------------------------------------------------------
__global__ void logits_kernel(const float* __restrict__ X,
                              const float* __restrict__ w,
                              const float* __restrict__ b,
                              float* __restrict__ logits,
                              int ngroups /* = NROWS/4 */) {
    const int lane        = threadIdx.x & 63;
    const int waveInBlock = threadIdx.x >> 6;
    const int wavesPerBlk = blockDim.x >> 6;
    const int sub         = lane & 15;   // position within a row's 16-lane team
    const int rowInGroup  = lane >> 4;   // 0..3

    long long gwave  = (long long)blockIdx.x * wavesPerBlk + waveInBlock;
    long long nwaves = (long long)gridDim.x * wavesPerBlk;

    const float4 w4 = reinterpret_cast<const float4*>(w)[sub];
    const float bias = b[0];

    for (long long g = gwave; g < ngroups; g += nwaves) {
        const float4* xp = reinterpret_cast<const float4*>(X) + g * 64;
        float4 x = xp[lane];
        float p = x.x * w4.x + x.y * w4.y + x.z * w4.z + x.w * w4.w;
        // reduce across the 16 lanes of this row's team (masks < 16 stay in-team)
        p += __shfl_xor(p, 1);
        p += __shfl_xor(p, 2);
        p += __shfl_xor(p, 4);
        p += __shfl_xor(p, 8);
        if (sub == 0) {
            logits[g * 4 + rowInGroup] = p + bias;
        }
    }
}

// ---------------------------------------------------------------------------
// Kernel 2a: init boundaries so empty segments are the empty range [0,0).
// ---------------------------------------------------------------------------
__global__ void init_bounds_kernel(int* __restrict__ seg_start,
                                   int* __restrict__ seg_end, int nseg) {
    int i = blockIdx.x * blockDim.x + threadIdx.x;
    if (i < nseg) { seg_start[i] = 0; seg_end[i] = 0; }
}

// ---------------------------------------------------------------------------
// Kernel 2b: seg_ids are sorted; mark run boundaries.
// ---------------------------------------------------------------------------
__global__ void find_bounds_kernel(const int* __restrict__ seg,
                                   int* __restrict__ seg_start,
                                   int* __restrict__ seg_end, int n) {
    int i = blockIdx.x * blockDim.x + threadIdx.x;
    if (i >= n) return;
    int s = seg[i];
    if (i == 0     || seg[i - 1] != s) seg_start[s] = i;
    if (i == n - 1 || seg[i + 1] != s) seg_end[s]   = i + 1;
}

// ---------------------------------------------------------------------------
// Kernel 3: per-segment softmax. One wave per segment; deterministic
// shuffle-tree reductions (no float atomics). Fast path: len <= 64 keeps the
// logit in a register; generic path re-reads logits (rare: P(len>64) ~1e-4).
// ---------------------------------------------------------------------------
__global__ void seg_softmax_kernel(const float* __restrict__ logits,
                                   const int* __restrict__ seg_start,
                                   const int* __restrict__ seg_end,
                                   float* __restrict__ out, int nseg) {
    const int lane = threadIdx.x & 63;
    const int wave = threadIdx.x >> 6;
    const int s = blockIdx.x * (blockDim.x >> 6) + wave;
    if (s >= nseg) return;

    const int start = seg_start[s];
    const int end   = seg_end[s];
    const int len   = end - start;

    if (len <= 64) {
        const bool act = lane < len;
        float x = act ? logits[start + lane] : -INFINITY;
        float mx = x;
        #pragma unroll
        for (int m = 1; m < 64; m <<= 1) mx = fmaxf(mx, __shfl_xor(mx, m));
        float e = act ? __expf(x - mx) : 0.0f;
        float sum = e;
        #pragma unroll
        for (int m = 1; m < 64; m <<= 1) sum += __shfl_xor(sum, m);
        if (act) out[start + lane] = e / sum;
    } else {
        float mx = -INFINITY;
        for (int i = start + lane; i < end; i += 64) mx = fmaxf(mx, logits[i]);
        #pragma unroll
        for (int m = 1; m < 64; m <<= 1) mx = fmaxf(mx, __shfl_xor(mx, m));
        float sum = 0.0f;
        for (int i = start + lane; i < end; i += 64) sum += __expf(logits[i] - mx);
        #pragma unroll
        for (int m = 1; m < 64; m <<= 1) sum += __shfl_xor(sum, m);
        const float inv = 1.0f / sum;
        for (int i = start + lane; i < end; i += 64)
            out[i] = __expf(logits[i] - mx) * inv;
    }
}

extern "C" void kernel_launch(void* const* d_in, const int* in_sizes, int n_in,
                              void* d_out, int out_size, void* d_ws, size_t ws_size,
                              hipStream_t stream) {
    const float* X    = (const float*)d_in[0];
    const int*   seg  = (const int*)d_in[1];
    const float* w    = (const float*)d_in[2];
    const float* b    = (const float*)d_in[3];
    float*       out  = (float*)d_out;

    // workspace layout: logits[NROWS] | seg_start[NSEG] | seg_end[NSEG]
    float* logits    = (float*)d_ws;
    int*   seg_start = (int*)((char*)d_ws + (size_t)NROWS * sizeof(float));
    int*   seg_end   = seg_start + NSEG;

    // 1) logits = X @ w + b
    const int ngroups = NROWS / 4;                 // 4 rows per wave-iteration
    logits_kernel<<<2048, 256, 0, stream>>>(X, w, b, logits, ngroups);

    // 2) segment boundaries (seg_ids sorted)
    init_bounds_kernel<<<(NSEG + 255) / 256, 256, 0, stream>>>(seg_start, seg_end, NSEG);
    find_bounds_kernel<<<NROWS / 256, 256, 0, stream>>>(seg, seg_start, seg_end, NROWS);

    // 3) per-segment softmax, one wave per segment, 4 waves per block
    const int wavesPerBlock = 4;
    const int nblocks = (NSEG + wavesPerBlock - 1) / wavesPerBlock;
    seg_softmax_kernel<<<nblocks, wavesPerBlock * 64, 0, stream>>>(
        logits, seg_start, seg_end, out, NSEG);
}

// Round 2
// 216.901 us; speedup vs baseline: 1.0343x; 1.0343x over previous
//
#include <hip/hip_runtime.h>
#include <math.h>

#define NROWS 4000000
#define DCOV  64
#define NSEG  100000

#define LOGITS_BLOCKS 2048
#define BOUNDS_BLOCKS 512

typedef float f32x4 __attribute__((ext_vector_type(4)));

// ---------------------------------------------------------------------------
// Kernel A (block-specialized fusion):
//   blocks [0, LOGITS_BLOCKS):              logits[i] = dot(X[i,:], w) + b
//   blocks [LOGITS_BLOCKS, +BOUNDS_BLOCKS): gap-filled segment starts st[0..NSEG]
// The bounds work (~32 MB) overlaps the X stream (1.02 GB) instead of
// serializing after it.
// ---------------------------------------------------------------------------
__global__ void fused_logits_bounds_kernel(const float* __restrict__ X,
                                           const float* __restrict__ w,
                                           const float* __restrict__ b,
                                           const int* __restrict__ seg,
                                           float* __restrict__ logits,
                                           int* __restrict__ st) {
    if (blockIdx.x < LOGITS_BLOCKS) {
        // ---- logits: wave-cooperative, 16 lanes per row, unroll x2 ----
        const int lane        = threadIdx.x & 63;
        const int waveInBlock = threadIdx.x >> 6;
        const int sub         = lane & 15;   // position within a row's 16-lane team
        const int rowInGroup  = lane >> 4;   // 0..3

        const long long nwaves = (long long)LOGITS_BLOCKS * 4;
        const long long gwave  = (long long)blockIdx.x * 4 + waveInBlock;
        const long long npairs = NROWS / 8;  // 8 rows (2 groups of 4) per iter

        const float4 w4 = reinterpret_cast<const float4*>(w)[sub];
        const float bias = b[0];

        const f32x4* Xv = reinterpret_cast<const f32x4*>(X);

        for (long long p = gwave; p < npairs; p += nwaves) {
            const f32x4* xp = Xv + p * 128;          // 2KB = 8 rows
            f32x4 x0 = __builtin_nontemporal_load(xp + lane);
            f32x4 x1 = __builtin_nontemporal_load(xp + 64 + lane);
            float p0 = x0.x * w4.x + x0.y * w4.y + x0.z * w4.z + x0.w * w4.w;
            float p1 = x1.x * w4.x + x1.y * w4.y + x1.z * w4.z + x1.w * w4.w;
            // reduce across each row's 16-lane team (xor masks < 16 stay in-team)
            p0 += __shfl_xor(p0, 1);  p1 += __shfl_xor(p1, 1);
            p0 += __shfl_xor(p0, 2);  p1 += __shfl_xor(p1, 2);
            p0 += __shfl_xor(p0, 4);  p1 += __shfl_xor(p1, 4);
            p0 += __shfl_xor(p0, 8);  p1 += __shfl_xor(p1, 8);
            if (sub == 0) {
                logits[p * 8 + rowInGroup]     = p0 + bias;
                logits[p * 8 + 4 + rowInGroup] = p1 + bias;
            }
        }
    } else {
        // ---- segment starts (seg_ids sorted): st[s] = first row of segment s,
        //      gap-filled so empty segments get st[s] == st[s+1]; st[NSEG] = N.
        const long long tid    = (long long)(blockIdx.x - LOGITS_BLOCKS) * blockDim.x
                               + threadIdx.x;
        const long long stride = (long long)BOUNDS_BLOCKS * blockDim.x;
        for (long long i = tid; i < NROWS; i += stride) {
            int s = seg[i];
            if (i == 0) {
                for (int t = 0; t <= s; ++t) st[t] = 0;
            } else {
                int prev = seg[i - 1];
                for (int t = prev + 1; t <= s; ++t) st[t] = (int)i;
            }
            if (i == NROWS - 1) {
                for (int t = s + 1; t <= NSEG; ++t) st[t] = NROWS;
            }
        }
    }
}

// ---------------------------------------------------------------------------
// Kernel B: per-segment softmax. One wave per segment; deterministic shuffle
// reductions. Fast path (len <= 64) keeps the logit in a register.
// ---------------------------------------------------------------------------
__global__ void seg_softmax_kernel(const float* __restrict__ logits,
                                   const int* __restrict__ st,
                                   float* __restrict__ out, int nseg) {
    const int lane = threadIdx.x & 63;
    const int wave = threadIdx.x >> 6;
    const int s = blockIdx.x * (blockDim.x >> 6) + wave;
    if (s >= nseg) return;

    const int start = st[s];
    const int end   = st[s + 1];
    const int len   = end - start;

    if (len <= 64) {
        const bool act = lane < len;
        float x = act ? logits[start + lane] : -INFINITY;
        float mx = x;
        #pragma unroll
        for (int m = 1; m < 64; m <<= 1) mx = fmaxf(mx, __shfl_xor(mx, m));
        float e = act ? __expf(x - mx) : 0.0f;
        float sum = e;
        #pragma unroll
        for (int m = 1; m < 64; m <<= 1) sum += __shfl_xor(sum, m);
        if (act) out[start + lane] = e / sum;
    } else {
        float mx = -INFINITY;
        for (int i = start + lane; i < end; i += 64) mx = fmaxf(mx, logits[i]);
        #pragma unroll
        for (int m = 1; m < 64; m <<= 1) mx = fmaxf(mx, __shfl_xor(mx, m));
        float sum = 0.0f;
        for (int i = start + lane; i < end; i += 64) sum += __expf(logits[i] - mx);
        #pragma unroll
        for (int m = 1; m < 64; m <<= 1) sum += __shfl_xor(sum, m);
        const float inv = 1.0f / sum;
        for (int i = start + lane; i < end; i += 64)
            out[i] = __expf(logits[i] - mx) * inv;
    }
}

extern "C" void kernel_launch(void* const* d_in, const int* in_sizes, int n_in,
                              void* d_out, int out_size, void* d_ws, size_t ws_size,
                              hipStream_t stream) {
    const float* X   = (const float*)d_in[0];
    const int*   seg = (const int*)d_in[1];
    const float* w   = (const float*)d_in[2];
    const float* b   = (const float*)d_in[3];
    float*       out = (float*)d_out;

    // workspace layout: logits[NROWS] | st[NSEG+1]
    float* logits = (float*)d_ws;
    int*   st     = (int*)((char*)d_ws + (size_t)NROWS * sizeof(float));

    fused_logits_bounds_kernel<<<LOGITS_BLOCKS + BOUNDS_BLOCKS, 256, 0, stream>>>(
        X, w, b, seg, logits, st);

    const int wavesPerBlock = 4;
    const int nblocks = (NSEG + wavesPerBlock - 1) / wavesPerBlock;
    seg_softmax_kernel<<<nblocks, wavesPerBlock * 64, 0, stream>>>(
        logits, st, out, NSEG);
}

// Round 3
// 209.563 us; speedup vs baseline: 1.0706x; 1.0350x over previous
//
#include <hip/hip_runtime.h>
#include <math.h>

#define NROWS 4000000
#define DCOV  64
#define NSEG  100000

#define LOGITS_BLOCKS 2048
#define BOUNDS_BLOCKS 512

typedef float f32x4 __attribute__((ext_vector_type(4)));

// ---------------------------------------------------------------------------
// Kernel A (block-specialized fusion):
//   blocks [0, LOGITS_BLOCKS):              logits[i] = dot(X[i,:], w) + b
//   blocks [LOGITS_BLOCKS, +BOUNDS_BLOCKS): gap-filled segment starts st[0..NSEG]
// Bounds work (~32 MB) overlaps the X stream (1.02 GB).
// ---------------------------------------------------------------------------
__global__ __launch_bounds__(256, 8)
void fused_logits_bounds_kernel(const float* __restrict__ X,
                                const float* __restrict__ w,
                                const float* __restrict__ b,
                                const int* __restrict__ seg,
                                float* __restrict__ logits,
                                int* __restrict__ st) {
    if (blockIdx.x < LOGITS_BLOCKS) {
        // ---- logits: wave-cooperative, 16 lanes per row, unroll x4 ----
        const int lane        = threadIdx.x & 63;
        const int waveInBlock = threadIdx.x >> 6;
        const int sub         = lane & 15;   // position within a row's 16-lane team
        const int rowInGroup  = lane >> 4;   // 0..3

        const long long nwaves = (long long)LOGITS_BLOCKS * 4;
        const long long gwave  = (long long)blockIdx.x * 4 + waveInBlock;
        const long long nquads = NROWS / 16; // 16 rows (4 groups of 4) per iter

        const float4 w4 = reinterpret_cast<const float4*>(w)[sub];
        const float bias = b[0];

        const f32x4* Xv = reinterpret_cast<const f32x4*>(X);

        for (long long q = gwave; q < nquads; q += nwaves) {
            const f32x4* xp = Xv + q * 256;          // 4KB = 16 rows
            f32x4 x0 = __builtin_nontemporal_load(xp + lane);
            f32x4 x1 = __builtin_nontemporal_load(xp + 64 + lane);
            f32x4 x2 = __builtin_nontemporal_load(xp + 128 + lane);
            f32x4 x3 = __builtin_nontemporal_load(xp + 192 + lane);
            float p0 = x0.x * w4.x + x0.y * w4.y + x0.z * w4.z + x0.w * w4.w;
            float p1 = x1.x * w4.x + x1.y * w4.y + x1.z * w4.z + x1.w * w4.w;
            float p2 = x2.x * w4.x + x2.y * w4.y + x2.z * w4.z + x2.w * w4.w;
            float p3 = x3.x * w4.x + x3.y * w4.y + x3.z * w4.z + x3.w * w4.w;
            // reduce across each row's 16-lane team (xor masks < 16 stay in-team)
            #pragma unroll
            for (int m = 1; m < 16; m <<= 1) {
                p0 += __shfl_xor(p0, m);
                p1 += __shfl_xor(p1, m);
                p2 += __shfl_xor(p2, m);
                p3 += __shfl_xor(p3, m);
            }
            if (sub == 0) {
                float* lp = logits + q * 16 + rowInGroup;
                lp[0]  = p0 + bias;
                lp[4]  = p1 + bias;
                lp[8]  = p2 + bias;
                lp[12] = p3 + bias;
            }
        }
    } else {
        // ---- segment starts (seg_ids sorted): st[s] = first row of segment s,
        //      gap-filled so empty segments get st[s] == st[s+1]; st[NSEG] = N.
        const long long tid    = (long long)(blockIdx.x - LOGITS_BLOCKS) * blockDim.x
                               + threadIdx.x;
        const long long stride = (long long)BOUNDS_BLOCKS * blockDim.x;
        for (long long i = tid; i < NROWS; i += stride) {
            int s = seg[i];
            if (i == 0) {
                for (int t = 0; t <= s; ++t) st[t] = 0;
            } else {
                int prev = seg[i - 1];
                for (int t = prev + 1; t <= s; ++t) st[t] = (int)i;
            }
            if (i == NROWS - 1) {
                for (int t = s + 1; t <= NSEG; ++t) st[t] = NROWS;
            }
        }
    }
}

// ---------------------------------------------------------------------------
// Kernel B: per-segment softmax, persistent grid-stride, 2 segments in
// flight per wave (ILP). Deterministic shuffle-tree reductions.
// ---------------------------------------------------------------------------
__device__ __forceinline__
void softmax_one(const float* __restrict__ logits, float* __restrict__ out,
                 int start, int end, int lane) {
    const int len = end - start;
    if (len <= 64) {
        const bool act = lane < len;
        float x = act ? logits[start + lane] : -INFINITY;
        float mx = x;
        #pragma unroll
        for (int m = 1; m < 64; m <<= 1) mx = fmaxf(mx, __shfl_xor(mx, m));
        float e = act ? __expf(x - mx) : 0.0f;
        float sum = e;
        #pragma unroll
        for (int m = 1; m < 64; m <<= 1) sum += __shfl_xor(sum, m);
        if (act) out[start + lane] = e / sum;
    } else {
        float mx = -INFINITY;
        for (int i = start + lane; i < end; i += 64) mx = fmaxf(mx, logits[i]);
        #pragma unroll
        for (int m = 1; m < 64; m <<= 1) mx = fmaxf(mx, __shfl_xor(mx, m));
        float sum = 0.0f;
        for (int i = start + lane; i < end; i += 64) sum += __expf(logits[i] - mx);
        #pragma unroll
        for (int m = 1; m < 64; m <<= 1) sum += __shfl_xor(sum, m);
        const float inv = 1.0f / sum;
        for (int i = start + lane; i < end; i += 64)
            out[i] = __expf(logits[i] - mx) * inv;
    }
}

__global__ __launch_bounds__(256, 8)
void seg_softmax_kernel(const float* __restrict__ logits,
                        const int* __restrict__ st,
                        float* __restrict__ out) {
    const int lane   = threadIdx.x & 63;
    const int gwave  = (blockIdx.x * blockDim.x + threadIdx.x) >> 6;
    const int nwaves = (gridDim.x * blockDim.x) >> 6;

    for (int s = gwave; s < NSEG; s += 2 * nwaves) {
        const int  s2   = s + nwaves;
        const bool has2 = (s2 < NSEG);
        const int a0 = st[s],  a1 = st[s + 1];
        const int b0 = has2 ? st[s2] : 0;
        const int b1 = has2 ? st[s2 + 1] : 0;
        const int lenA = a1 - a0;
        const int lenB = b1 - b0;

        if (lenA <= 64 && lenB <= 64) {
            // two independent softmaxes in flight — hides gather latency
            const bool actA = lane < lenA;
            const bool actB = has2 && (lane < lenB);
            float xA = actA ? logits[a0 + lane] : -INFINITY;
            float xB = actB ? logits[b0 + lane] : -INFINITY;
            float mA = xA, mB = xB;
            #pragma unroll
            for (int m = 1; m < 64; m <<= 1) {
                mA = fmaxf(mA, __shfl_xor(mA, m));
                mB = fmaxf(mB, __shfl_xor(mB, m));
            }
            float eA = actA ? __expf(xA - mA) : 0.0f;
            float eB = actB ? __expf(xB - mB) : 0.0f;
            float sA = eA, sB = eB;
            #pragma unroll
            for (int m = 1; m < 64; m <<= 1) {
                sA += __shfl_xor(sA, m);
                sB += __shfl_xor(sB, m);
            }
            if (actA) out[a0 + lane] = eA / sA;
            if (actB) out[b0 + lane] = eB / sB;
        } else {
            softmax_one(logits, out, a0, a1, lane);
            if (has2) softmax_one(logits, out, b0, b1, lane);
        }
    }
}

extern "C" void kernel_launch(void* const* d_in, const int* in_sizes, int n_in,
                              void* d_out, int out_size, void* d_ws, size_t ws_size,
                              hipStream_t stream) {
    const float* X   = (const float*)d_in[0];
    const int*   seg = (const int*)d_in[1];
    const float* w   = (const float*)d_in[2];
    const float* b   = (const float*)d_in[3];
    float*       out = (float*)d_out;

    // workspace layout: logits[NROWS] | st[NSEG+1]
    float* logits = (float*)d_ws;
    int*   st     = (int*)((char*)d_ws + (size_t)NROWS * sizeof(float));

    fused_logits_bounds_kernel<<<LOGITS_BLOCKS + BOUNDS_BLOCKS, 256, 0, stream>>>(
        X, w, b, seg, logits, st);

    seg_softmax_kernel<<<2048, 256, 0, stream>>>(logits, st, out);
}

// Round 4
// 185.386 us; speedup vs baseline: 1.2102x; 1.1304x over previous
//
#include <hip/hip_runtime.h>
#include <math.h>

#define NROWS 4000000
#define DCOV  64
#define NSEG  100000

#define SEGS_PER_BLOCK 25
#define NBLOCKS (NSEG / SEGS_PER_BLOCK)   // 4000
#define CAP 2048                          // LDS logit slots (avg rows/block ~1000, sigma ~32)

typedef float f32x4 __attribute__((ext_vector_type(4)));

// ---------------------------------------------------------------------------
// Single fused kernel. Block b owns segments [b*25, b*25+25):
//   phase 0 : binary search seg (sorted) for the block's row range
//   phase 0b: gap-filled segment starts into LDS (empty segs -> zero-len)
//   phase 1 : logits = X@w + b straight into LDS (wave-coop, 16 lanes/row)
//   phase 2 : per-wave softmax per segment, in-place in LDS
//   phase 3 : contiguous coalesced write of the block's out range
// Fallback (never expected: nrows > CAP) routes logits via global d_ws.
// ---------------------------------------------------------------------------
__global__ __launch_bounds__(256, 8)
void fused_clr_kernel(const float* __restrict__ X,
                      const int* __restrict__ seg,
                      const float* __restrict__ w,
                      const float* __restrict__ b,
                      float* __restrict__ out,
                      float* __restrict__ gl /* global logits fallback */) {
    __shared__ int   st_lds[SEGS_PER_BLOCK + 1];
    __shared__ float logit_lds[CAP];
    __shared__ int   rs_sh, re_sh;

    const int tid  = threadIdx.x;
    const int lane = tid & 63;
    const int wv   = tid >> 6;          // wave in block, 0..3
    const int sub  = lane & 15;         // position in the row's 16-lane team
    const int rig  = lane >> 4;         // row within 4-row group

    const int s0 = blockIdx.x * SEGS_PER_BLOCK;
    const int s1 = s0 + SEGS_PER_BLOCK;

    // ---- phase 0: row range via binary search (threads 0,1 concurrently) ----
    if (tid < 2) {
        const int target = (tid == 0) ? s0 : s1;
        int lo = 0, hi = NROWS;
        while (lo < hi) {
            int mid = (lo + hi) >> 1;
            if (seg[mid] < target) lo = mid + 1; else hi = mid;
        }
        if (tid == 0) rs_sh = lo; else re_sh = lo;
    }
    __syncthreads();
    const int row_start = rs_sh;
    const int row_end   = re_sh;
    const int nrows     = row_end - row_start;

    // ---- phase 0b: segment starts, gap-filled ----
    for (int j = tid; j <= SEGS_PER_BLOCK; j += 256) st_lds[j] = row_end;
    __syncthreads();
    for (int i = row_start + tid; i < row_end; i += 256) {
        int s    = seg[i];
        int prev = (i == row_start) ? (s0 - 1) : seg[i - 1];
        for (int t = prev + 1; t <= s; ++t) st_lds[t - s0] = i;
    }

    const bool  use_lds = (nrows <= CAP);
    const float bias    = b[0];
    const float4 w4     = reinterpret_cast<const float4*>(w)[sub];
    const f32x4* Xv     = reinterpret_cast<const f32x4*>(X);

    __syncthreads();

    // ---- phase 1: logits, 16 rows per wave per iteration (4 loads in flight) ----
    for (int rb = row_start + wv * 16; rb < row_end; rb += 64) {
        const int r0 = rb + rig, r1 = rb + 4 + rig, r2 = rb + 8 + rig, r3 = rb + 12 + rig;
        f32x4 x0 = {0,0,0,0}, x1 = {0,0,0,0}, x2 = {0,0,0,0}, x3 = {0,0,0,0};
        const f32x4* xp = Xv + (long long)rb * 16 + lane;
        if (r0 < row_end) x0 = __builtin_nontemporal_load(xp);
        if (r1 < row_end) x1 = __builtin_nontemporal_load(xp + 64);
        if (r2 < row_end) x2 = __builtin_nontemporal_load(xp + 128);
        if (r3 < row_end) x3 = __builtin_nontemporal_load(xp + 192);
        float p0 = x0.x * w4.x + x0.y * w4.y + x0.z * w4.z + x0.w * w4.w;
        float p1 = x1.x * w4.x + x1.y * w4.y + x1.z * w4.z + x1.w * w4.w;
        float p2 = x2.x * w4.x + x2.y * w4.y + x2.z * w4.z + x2.w * w4.w;
        float p3 = x3.x * w4.x + x3.y * w4.y + x3.z * w4.z + x3.w * w4.w;
        #pragma unroll
        for (int m = 1; m < 16; m <<= 1) {      // 16-lane team reduce
            p0 += __shfl_xor(p0, m);
            p1 += __shfl_xor(p1, m);
            p2 += __shfl_xor(p2, m);
            p3 += __shfl_xor(p3, m);
        }
        if (sub == 0) {
            if (use_lds) {
                if (r0 < row_end) logit_lds[r0 - row_start] = p0 + bias;
                if (r1 < row_end) logit_lds[r1 - row_start] = p1 + bias;
                if (r2 < row_end) logit_lds[r2 - row_start] = p2 + bias;
                if (r3 < row_end) logit_lds[r3 - row_start] = p3 + bias;
            } else {
                if (r0 < row_end) gl[r0] = p0 + bias;
                if (r1 < row_end) gl[r1] = p1 + bias;
                if (r2 < row_end) gl[r2] = p2 + bias;
                if (r3 < row_end) gl[r3] = p3 + bias;
            }
        }
    }
    __syncthreads();

    // ---- phase 2: per-segment softmax (one wave per segment, in place) ----
    for (int j = wv; j < SEGS_PER_BLOCK; j += 4) {
        const int a0  = st_lds[j];
        const int a1  = st_lds[j + 1];
        const int len = a1 - a0;
        if (len <= 0) continue;                 // wave-uniform
        if (len <= 64) {
            const bool act = lane < len;
            const int  idx = a0 - row_start + lane;
            float x = act ? (use_lds ? logit_lds[idx] : gl[a0 + lane]) : -INFINITY;
            float mx = x;
            #pragma unroll
            for (int m = 1; m < 64; m <<= 1) mx = fmaxf(mx, __shfl_xor(mx, m));
            float e = act ? __expf(x - mx) : 0.0f;
            float sum = e;
            #pragma unroll
            for (int m = 1; m < 64; m <<= 1) sum += __shfl_xor(sum, m);
            const float pr = e / sum;
            if (act) {
                if (use_lds) logit_lds[idx] = pr;
                else         out[a0 + lane] = pr;
            }
        } else {
            float mx = -INFINITY;
            for (int i = a0 + lane; i < a1; i += 64)
                mx = fmaxf(mx, use_lds ? logit_lds[i - row_start] : gl[i]);
            #pragma unroll
            for (int m = 1; m < 64; m <<= 1) mx = fmaxf(mx, __shfl_xor(mx, m));
            float sum = 0.0f;
            for (int i = a0 + lane; i < a1; i += 64)
                sum += __expf((use_lds ? logit_lds[i - row_start] : gl[i]) - mx);
            #pragma unroll
            for (int m = 1; m < 64; m <<= 1) sum += __shfl_xor(sum, m);
            const float inv = 1.0f / sum;
            for (int i = a0 + lane; i < a1; i += 64) {
                float pr = __expf((use_lds ? logit_lds[i - row_start] : gl[i]) - mx) * inv;
                if (use_lds) logit_lds[i - row_start] = pr;
                else         out[i] = pr;
            }
        }
    }
    __syncthreads();

    // ---- phase 3: coalesced contiguous output write ----
    if (use_lds) {
        for (int i = tid; i < nrows; i += 256)
            out[row_start + i] = logit_lds[i];
    }
}

extern "C" void kernel_launch(void* const* d_in, const int* in_sizes, int n_in,
                              void* d_out, int out_size, void* d_ws, size_t ws_size,
                              hipStream_t stream) {
    const float* X   = (const float*)d_in[0];
    const int*   seg = (const int*)d_in[1];
    const float* w   = (const float*)d_in[2];
    const float* b   = (const float*)d_in[3];
    float*       out = (float*)d_out;
    float*       gl  = (float*)d_ws;    // fallback logits buffer (normally unused)

    fused_clr_kernel<<<NBLOCKS, 256, 0, stream>>>(X, seg, w, b, out, gl);
}

// Round 5
// 183.348 us; speedup vs baseline: 1.2236x; 1.0111x over previous
//
#include <hip/hip_runtime.h>
#include <math.h>

#define NROWS 4000000
#define DCOV  64
#define NSEG  100000

#define SEGS_PER_BLOCK 25
#define NBLOCKS (NSEG / SEGS_PER_BLOCK)   // 4000
#define CAP 2048                          // LDS logit slots (avg rows/block ~1000, sigma ~32)

typedef float f32x4 __attribute__((ext_vector_type(4)));

// 64-lane cooperative lower_bound over sorted seg[0..NROWS): 64-ary search,
// 4 rounds of parallel probes instead of ~22 serial dependent loads.
__device__ __forceinline__ int lower_bound_seg(const int* __restrict__ seg,
                                               int target, int lane) {
    int lo = 0, n = NROWS;
    while (n > 64) {
        const int step = (n + 63) >> 6;                 // ceil(n/64)
        const long long p = (long long)lo + (long long)(lane + 1) * step;
        const bool lt = (p < (long long)lo + n) && (seg[p] < target);
        const int cnt = (int)__popcll(__ballot(lt));    // lanes with lt form a prefix
        lo += cnt * step;
        n = min(step, n - cnt * step);
    }
    const bool lt = (lane < n) && (seg[lo + lane] < target);
    return lo + (int)__popcll(__ballot(lt));
}

// ---------------------------------------------------------------------------
// Single fused kernel, 2 barriers per block. Block b owns segments
// [b*25, b*25+25):
//   phase 0 : wave-parallel 64-ary search for the block's row range  | barrier
//   phase 1 : gap-filled segment starts into LDS, then logits = X@w+b
//             straight into LDS (wave-coop, 16 lanes/row, x4 unroll) | barrier
//   phase 2 : per-wave softmax per segment, written DIRECTLY to out (NT)
// Fallback (never expected: nrows > CAP) routes logits via global d_ws.
// ---------------------------------------------------------------------------
__global__ __launch_bounds__(256, 8)
void fused_clr_kernel(const float* __restrict__ X,
                      const int* __restrict__ seg,
                      const float* __restrict__ w,
                      const float* __restrict__ b,
                      float* __restrict__ out,
                      float* __restrict__ gl /* global logits fallback */) {
    __shared__ int   st_lds[SEGS_PER_BLOCK + 1];
    __shared__ float logit_lds[CAP];
    __shared__ int   rs_sh, re_sh;

    const int tid  = threadIdx.x;
    const int lane = tid & 63;
    const int wv   = tid >> 6;          // wave in block, 0..3
    const int sub  = lane & 15;         // position in the row's 16-lane team
    const int rig  = lane >> 4;         // row within 4-row group

    const int s0 = blockIdx.x * SEGS_PER_BLOCK;
    const int s1 = s0 + SEGS_PER_BLOCK;

    // ---- phase 0: row range (waves 0 and 1 search concurrently) ----
    if (wv == 0) {
        int r = lower_bound_seg(seg, s0, lane);
        if (lane == 0) rs_sh = r;
    } else if (wv == 1) {
        int r = lower_bound_seg(seg, s1, lane);
        if (lane == 0) re_sh = r;
    }
    __syncthreads();
    const int row_start = rs_sh;
    const int row_end   = re_sh;
    const int nrows     = row_end - row_start;

    const bool  use_lds = (nrows <= CAP);
    const float bias    = b[0];
    const float4 w4     = reinterpret_cast<const float4*>(w)[sub];
    const f32x4* Xv     = reinterpret_cast<const f32x4*>(X);

    // ---- phase 1a: segment starts, gap-filled (each entry has exactly one
    //      writer: the first row i with seg[i] >= t). Tail entries filled by
    //      the owner of the last row. ----
    if (nrows == 0) {
        if (tid <= SEGS_PER_BLOCK) st_lds[tid] = row_end;
    } else {
        for (int i = row_start + tid; i < row_end; i += 256) {
            const int s    = seg[i];
            const int prev = (i == row_start) ? (s0 - 1) : seg[i - 1];
            for (int t = prev + 1; t <= s; ++t) st_lds[t - s0] = i;
            if (i == row_end - 1) {
                for (int t = s + 1; t <= s1; ++t) st_lds[t - s0] = row_end;
            }
        }
    }

    // ---- phase 1b: logits, 16 rows per wave per iteration (4 loads in flight) ----
    for (int rb = row_start + wv * 16; rb < row_end; rb += 64) {
        const int r0 = rb + rig, r1 = rb + 4 + rig, r2 = rb + 8 + rig, r3 = rb + 12 + rig;
        f32x4 x0 = {0,0,0,0}, x1 = {0,0,0,0}, x2 = {0,0,0,0}, x3 = {0,0,0,0};
        const f32x4* xp = Xv + (long long)rb * 16 + lane;
        if (r0 < row_end) x0 = __builtin_nontemporal_load(xp);
        if (r1 < row_end) x1 = __builtin_nontemporal_load(xp + 64);
        if (r2 < row_end) x2 = __builtin_nontemporal_load(xp + 128);
        if (r3 < row_end) x3 = __builtin_nontemporal_load(xp + 192);
        float p0 = x0.x * w4.x + x0.y * w4.y + x0.z * w4.z + x0.w * w4.w;
        float p1 = x1.x * w4.x + x1.y * w4.y + x1.z * w4.z + x1.w * w4.w;
        float p2 = x2.x * w4.x + x2.y * w4.y + x2.z * w4.z + x2.w * w4.w;
        float p3 = x3.x * w4.x + x3.y * w4.y + x3.z * w4.z + x3.w * w4.w;
        #pragma unroll
        for (int m = 1; m < 16; m <<= 1) {      // 16-lane team reduce
            p0 += __shfl_xor(p0, m);
            p1 += __shfl_xor(p1, m);
            p2 += __shfl_xor(p2, m);
            p3 += __shfl_xor(p3, m);
        }
        if (sub == 0) {
            if (use_lds) {
                if (r0 < row_end) logit_lds[r0 - row_start] = p0 + bias;
                if (r1 < row_end) logit_lds[r1 - row_start] = p1 + bias;
                if (r2 < row_end) logit_lds[r2 - row_start] = p2 + bias;
                if (r3 < row_end) logit_lds[r3 - row_start] = p3 + bias;
            } else {
                if (r0 < row_end) gl[r0] = p0 + bias;
                if (r1 < row_end) gl[r1] = p1 + bias;
                if (r2 < row_end) gl[r2] = p2 + bias;
                if (r3 < row_end) gl[r3] = p3 + bias;
            }
        }
    }
    __syncthreads();

    // ---- phase 2: per-segment softmax (one wave per segment), direct NT
    //      writes to out ----
    for (int j = wv; j < SEGS_PER_BLOCK; j += 4) {
        const int a0  = st_lds[j];
        const int a1  = st_lds[j + 1];
        const int len = a1 - a0;
        if (len <= 0) continue;                 // wave-uniform
        if (len <= 64) {
            const bool act = lane < len;
            const int  idx = a0 - row_start + lane;
            float x = act ? (use_lds ? logit_lds[idx] : gl[a0 + lane]) : -INFINITY;
            float mx = x;
            #pragma unroll
            for (int m = 1; m < 64; m <<= 1) mx = fmaxf(mx, __shfl_xor(mx, m));
            float e = act ? __expf(x - mx) : 0.0f;
            float sum = e;
            #pragma unroll
            for (int m = 1; m < 64; m <<= 1) sum += __shfl_xor(sum, m);
            if (act) __builtin_nontemporal_store(e / sum, &out[a0 + lane]);
        } else {
            float mx = -INFINITY;
            for (int i = a0 + lane; i < a1; i += 64)
                mx = fmaxf(mx, use_lds ? logit_lds[i - row_start] : gl[i]);
            #pragma unroll
            for (int m = 1; m < 64; m <<= 1) mx = fmaxf(mx, __shfl_xor(mx, m));
            float sum = 0.0f;
            for (int i = a0 + lane; i < a1; i += 64)
                sum += __expf((use_lds ? logit_lds[i - row_start] : gl[i]) - mx);
            #pragma unroll
            for (int m = 1; m < 64; m <<= 1) sum += __shfl_xor(sum, m);
            const float inv = 1.0f / sum;
            for (int i = a0 + lane; i < a1; i += 64) {
                float pr = __expf((use_lds ? logit_lds[i - row_start] : gl[i]) - mx) * inv;
                __builtin_nontemporal_store(pr, &out[i]);
            }
        }
    }
}

extern "C" void kernel_launch(void* const* d_in, const int* in_sizes, int n_in,
                              void* d_out, int out_size, void* d_ws, size_t ws_size,
                              hipStream_t stream) {
    const float* X   = (const float*)d_in[0];
    const int*   seg = (const int*)d_in[1];
    const float* w   = (const float*)d_in[2];
    const float* b   = (const float*)d_in[3];
    float*       out = (float*)d_out;
    float*       gl  = (float*)d_ws;    // fallback logits buffer (normally unused)

    fused_clr_kernel<<<NBLOCKS, 256, 0, stream>>>(X, seg, w, b, out, gl);
}